// Round 1
// baseline (1607.093 us; speedup 1.0000x reference)
//
#include <hip/hip_runtime.h>
#include <math.h>

#define N_NODES 100000
#define N_EDGES 3200000
#define IN_CH   256
#define HID     64
#define OUTC    32

// ---------------- workspace layout (bytes) ----------------
static constexpr size_t align256(size_t x) { return (x + 255) & ~(size_t)255; }
static constexpr size_t OFF_CNT = 0;                                        // N ints
static constexpr size_t OFF_DIS = align256((size_t)N_NODES * 4);            // N floats
static constexpr size_t OFF_S1  = OFF_DIS + align256((size_t)N_NODES * 4);  // N*64 floats
static constexpr size_t OFF_A1  = OFF_S1 + (size_t)N_NODES * HID * 4;       // N*64 floats
static constexpr size_t OFF_S2  = OFF_A1 + (size_t)N_NODES * HID * 4;       // N*32 floats
static constexpr size_t OFF_A2  = OFF_S2 + (size_t)N_NODES * OUTC * 4;      // N*32 floats
// total ≈ 77.6 MB

// ---------------- degree / norm ----------------
__global__ __launch_bounds__(256) void count_deg(const int* __restrict__ col,
                                                 int* __restrict__ cnt) {
    unsigned e = blockIdx.x * 256u + threadIdx.x;
    if (e < N_EDGES) atomicAdd(&cnt[col[e]], 1);
}

__global__ __launch_bounds__(256) void compute_dis(const int* __restrict__ cnt,
                                                   float* __restrict__ dis) {
    unsigned v = blockIdx.x * 256u + threadIdx.x;
    if (v < N_NODES) dis[v] = rsqrtf((float)cnt[v] + 1.0f);  // +1 self-loop
}

// ---------------- GEMM1: s1[n][j] = dis[n] * (x[n,:] @ W1[:,j]); acc1 = s1 (self-loop init)
// block = 256 = 4 groups of 64 lanes; each group does 4 rows; 16 rows/block; 6250 blocks exact.
__global__ __launch_bounds__(256) void gemm1(const float* __restrict__ x,
                                             const float* __restrict__ W1,
                                             const float* __restrict__ dis,
                                             float* __restrict__ s1,
                                             float* __restrict__ acc1) {
    const int j  = threadIdx.x & 63;
    const int g  = threadIdx.x >> 6;
    const int n0 = blockIdx.x * 16 + g * 4;
    const float* x0 = x + (size_t)n0 * IN_CH;
    float a0 = 0.f, a1 = 0.f, a2 = 0.f, a3 = 0.f;
#pragma unroll 4
    for (int k = 0; k < IN_CH; ++k) {
        float w = W1[k * HID + j];
        a0 += x0[k] * w;
        a1 += x0[IN_CH + k] * w;
        a2 += x0[2 * IN_CH + k] * w;
        a3 += x0[3 * IN_CH + k] * w;
    }
    size_t o = (size_t)n0 * HID + j;
    float d0 = dis[n0], d1 = dis[n0 + 1], d2 = dis[n0 + 2], d3 = dis[n0 + 3];
    float v0 = d0 * a0, v1 = d1 * a1, v2 = d2 * a2, v3 = d3 * a3;
    s1[o] = v0;           acc1[o] = v0;
    s1[o + HID] = v1;     acc1[o + HID] = v1;
    s1[o + 2 * HID] = v2; acc1[o + 2 * HID] = v2;
    s1[o + 3 * HID] = v3; acc1[o + 3 * HID] = v3;
}

// ---------------- edge scatter, layer 1: acc1[v][j] += s1[u][j]
__global__ __launch_bounds__(256) void scatter1(const int* __restrict__ row,
                                                const int* __restrict__ col,
                                                const float* __restrict__ s1,
                                                float* __restrict__ acc1) {
    unsigned gid = blockIdx.x * 256u + threadIdx.x;
    unsigned e = gid >> 6;
    unsigned j = gid & 63u;
    if (e < N_EDGES) {
        int u = row[e], v = col[e];
        atomicAdd(acc1 + (size_t)v * HID + j, s1[(size_t)u * HID + j]);
    }
}

// ---------------- epilogue layer 1: h1e = ELU(dis[v]*acc1 + b1), in-place
__global__ __launch_bounds__(256) void elu1(float* __restrict__ acc1,
                                            const float* __restrict__ dis,
                                            const float* __restrict__ b1) {
    unsigned idx = blockIdx.x * 256u + threadIdx.x;  // N*64 threads exact
    unsigned v = idx >> 6, j = idx & 63u;
    float t = dis[v] * acc1[idx] + b1[j];
    acc1[idx] = t > 0.f ? t : (expf(t) - 1.f);
}

// ---------------- GEMM2: s2[n][j] = dis[n] * (h1e[n,:] @ W2[:,j]); acc2 = s2
// block = 256 = 8 groups of 32 lanes; each group 4 rows; 32 rows/block; 3125 blocks exact.
__global__ __launch_bounds__(256) void gemm2(const float* __restrict__ h,
                                             const float* __restrict__ W2,
                                             const float* __restrict__ dis,
                                             float* __restrict__ s2,
                                             float* __restrict__ acc2) {
    const int j  = threadIdx.x & 31;
    const int g  = threadIdx.x >> 5;
    const int n0 = blockIdx.x * 32 + g * 4;
    const float* h0 = h + (size_t)n0 * HID;
    float a0 = 0.f, a1 = 0.f, a2 = 0.f, a3 = 0.f;
#pragma unroll 4
    for (int k = 0; k < HID; ++k) {
        float w = W2[k * OUTC + j];
        a0 += h0[k] * w;
        a1 += h0[HID + k] * w;
        a2 += h0[2 * HID + k] * w;
        a3 += h0[3 * HID + k] * w;
    }
    size_t o = (size_t)n0 * OUTC + j;
    float d0 = dis[n0], d1 = dis[n0 + 1], d2 = dis[n0 + 2], d3 = dis[n0 + 3];
    float v0 = d0 * a0, v1 = d1 * a1, v2 = d2 * a2, v3 = d3 * a3;
    s2[o] = v0;            acc2[o] = v0;
    s2[o + OUTC] = v1;     acc2[o + OUTC] = v1;
    s2[o + 2 * OUTC] = v2; acc2[o + 2 * OUTC] = v2;
    s2[o + 3 * OUTC] = v3; acc2[o + 3 * OUTC] = v3;
}

// ---------------- edge scatter, layer 2
__global__ __launch_bounds__(256) void scatter2(const int* __restrict__ row,
                                                const int* __restrict__ col,
                                                const float* __restrict__ s2,
                                                float* __restrict__ acc2) {
    unsigned gid = blockIdx.x * 256u + threadIdx.x;
    unsigned e = gid >> 5;
    unsigned j = gid & 31u;
    if (e < N_EDGES) {
        int u = row[e], v = col[e];
        atomicAdd(acc2 + (size_t)v * OUTC + j, s2[(size_t)u * OUTC + j]);
    }
}

// ---------------- final: out[v] = ELU(dis[v]*acc2[v,:] + b2) @ Wc + bc
// 32 lanes per node, shuffle reduce; N*32 threads = 12500 blocks exact.
__global__ __launch_bounds__(256) void final_out(const float* __restrict__ acc2,
                                                 const float* __restrict__ dis,
                                                 const float* __restrict__ b2,
                                                 const float* __restrict__ Wc,
                                                 const float* __restrict__ bc,
                                                 float* __restrict__ out) {
    unsigned gid = blockIdx.x * 256u + threadIdx.x;
    unsigned v = gid >> 5, j = gid & 31u;
    float t = dis[v] * acc2[(size_t)v * OUTC + j] + b2[j];
    float hh = t > 0.f ? t : (expf(t) - 1.f);
    float p = hh * Wc[j];
#pragma unroll
    for (int off = 16; off > 0; off >>= 1) p += __shfl_xor(p, off, 64);
    if (j == 0) out[v] = p + bc[0];
}

extern "C" void kernel_launch(void* const* d_in, const int* in_sizes, int n_in,
                              void* d_out, int out_size, void* d_ws, size_t ws_size,
                              hipStream_t stream) {
    const float* x  = (const float*)d_in[0];
    const int*   ei = (const int*)d_in[1];   // int32 (JAX x64-disabled downcasts int64)
    const float* W1 = (const float*)d_in[2];
    const float* b1 = (const float*)d_in[3];
    const float* W2 = (const float*)d_in[4];
    const float* b2 = (const float*)d_in[5];
    const float* Wc = (const float*)d_in[6];
    const float* bc = (const float*)d_in[7];
    float* out = (float*)d_out;

    const int* row = ei;            // edge_index[0] = source
    const int* col = ei + N_EDGES;  // edge_index[1] = target

    char* ws = (char*)d_ws;
    int*   cnt  = (int*)  (ws + OFF_CNT);
    float* dis  = (float*)(ws + OFF_DIS);
    float* s1   = (float*)(ws + OFF_S1);
    float* acc1 = (float*)(ws + OFF_A1);
    float* s2   = (float*)(ws + OFF_S2);
    float* acc2 = (float*)(ws + OFF_A2);

    hipMemsetAsync(cnt, 0, (size_t)N_NODES * sizeof(int), stream);

    count_deg  <<<(N_EDGES + 255) / 256, 256, 0, stream>>>(col, cnt);
    compute_dis<<<(N_NODES + 255) / 256, 256, 0, stream>>>(cnt, dis);

    gemm1<<<N_NODES / 16, 256, 0, stream>>>(x, W1, dis, s1, acc1);
    scatter1<<<(size_t)N_EDGES * HID / 256, 256, 0, stream>>>(row, col, s1, acc1);
    elu1<<<(size_t)N_NODES * HID / 256, 256, 0, stream>>>(acc1, dis, b1);

    gemm2<<<N_NODES / 32, 256, 0, stream>>>(acc1, W2, dis, s2, acc2);
    scatter2<<<(size_t)N_EDGES * OUTC / 256, 256, 0, stream>>>(row, col, s2, acc2);

    final_out<<<(size_t)N_NODES * OUTC / 256, 256, 0, stream>>>(acc2, dis, b2, Wc, bc, out);
}

// Round 2
// 1010.776 us; speedup vs baseline: 1.5900x; 1.5900x over previous
//
#include <hip/hip_runtime.h>
#include <math.h>

#define N_NODES 100000
#define N_EDGES 3200000
#define IN_CH   256
#define HID     64
#define OUTC    32
#define NB      ((N_NODES + 255) / 256)   // 391 scan blocks

// ---------------- workspace layout (bytes) ----------------
static constexpr size_t align256(size_t x) { return (x + 255) & ~(size_t)255; }
static constexpr size_t OFF_DEG  = 0;                                          // N ints
static constexpr size_t OFF_PTR  = OFF_DEG  + align256((size_t)N_NODES * 4);   // N ints (exclusive prefix; becomes inclusive after fill)
static constexpr size_t OFF_BSUM = OFF_PTR  + align256((size_t)N_NODES * 4);   // 512 ints
static constexpr size_t OFF_DIS  = OFF_BSUM + align256(512 * 4);               // N floats
static constexpr size_t OFF_SRC  = OFF_DIS  + align256((size_t)N_NODES * 4);   // E ints (sorted-by-dst source ids)
static constexpr size_t OFF_S1   = OFF_SRC  + align256((size_t)N_EDGES * 4);   // N*64 floats (s1; later reused as s2 N*32)
static constexpr size_t OFF_H1   = OFF_S1   + (size_t)N_NODES * HID * 4;       // N*64 floats
// total ≈ 65.5 MB

// ---------------- degree ----------------
__global__ __launch_bounds__(256) void count_deg(const int* __restrict__ col,
                                                 int* __restrict__ deg) {
    unsigned e = blockIdx.x * 256u + threadIdx.x;
    if (e < N_EDGES) atomicAdd(&deg[col[e]], 1);
}

__global__ __launch_bounds__(256) void compute_dis(const int* __restrict__ deg,
                                                   float* __restrict__ dis) {
    unsigned v = blockIdx.x * 256u + threadIdx.x;
    if (v < N_NODES) dis[v] = rsqrtf((float)deg[v] + 1.0f);  // +1 self-loop
}

// ---------------- 3-kernel exclusive scan of deg -> ptr ----------------
__global__ __launch_bounds__(256) void scan_block_sums(const int* __restrict__ deg,
                                                       int* __restrict__ bsum) {
    __shared__ int buf[256];
    unsigned i = blockIdx.x * 256u + threadIdx.x;
    int v = (i < N_NODES) ? deg[i] : 0;
    buf[threadIdx.x] = v;
    __syncthreads();
    for (int off = 128; off > 0; off >>= 1) {
        if (threadIdx.x < (unsigned)off) buf[threadIdx.x] += buf[threadIdx.x + off];
        __syncthreads();
    }
    if (threadIdx.x == 0) bsum[blockIdx.x] = buf[0];
}

__global__ __launch_bounds__(512) void scan_bsum(int* __restrict__ bsum) {
    __shared__ int buf[512];
    int t = threadIdx.x;
    int v = (t < NB) ? bsum[t] : 0;
    buf[t] = v;
    __syncthreads();
    for (int off = 1; off < 512; off <<= 1) {
        int add = (t >= off) ? buf[t - off] : 0;
        __syncthreads();
        buf[t] += add;
        __syncthreads();
    }
    if (t < NB) bsum[t] = buf[t] - v;  // exclusive
}

__global__ __launch_bounds__(256) void scan_block_scan(const int* __restrict__ deg,
                                                       const int* __restrict__ bsum,
                                                       int* __restrict__ ptr) {
    __shared__ int buf[256];
    unsigned i = blockIdx.x * 256u + threadIdx.x;
    int v = (i < N_NODES) ? deg[i] : 0;
    buf[threadIdx.x] = v;
    __syncthreads();
    for (int off = 1; off < 256; off <<= 1) {
        int add = (threadIdx.x >= (unsigned)off) ? buf[threadIdx.x - off] : 0;
        __syncthreads();
        buf[threadIdx.x] += add;
        __syncthreads();
    }
    if (i < N_NODES) ptr[i] = bsum[blockIdx.x] + buf[threadIdx.x] - v;  // exclusive
}

// ---------------- CSR fill: ptr doubles as cursor (post: ptr[v] = segment end) ----
__global__ __launch_bounds__(256) void csr_fill(const int* __restrict__ row,
                                                const int* __restrict__ col,
                                                int* __restrict__ ptr,
                                                int* __restrict__ srcs) {
    unsigned e = blockIdx.x * 256u + threadIdx.x;
    if (e < N_EDGES) {
        int v = col[e];
        int pos = atomicAdd(&ptr[v], 1);
        srcs[pos] = row[e];
    }
}

// ---------------- GEMM1: s1[n][j] = dis[n] * (x[n,:] @ W1[:,j]) ----------------
// block = 256 = 4 waves; each wave does 4 rows; 16 rows/block; 6250 blocks exact.
__global__ __launch_bounds__(256) void gemm1(const float* __restrict__ x,
                                             const float* __restrict__ W1,
                                             const float* __restrict__ dis,
                                             float* __restrict__ s1) {
    const int j  = threadIdx.x & 63;
    const int g  = threadIdx.x >> 6;
    const int n0 = blockIdx.x * 16 + g * 4;
    const float* x0 = x + (size_t)n0 * IN_CH;
    float a0 = 0.f, a1 = 0.f, a2 = 0.f, a3 = 0.f;
#pragma unroll 4
    for (int k = 0; k < IN_CH; ++k) {
        float w = W1[k * HID + j];
        a0 += x0[k] * w;
        a1 += x0[IN_CH + k] * w;
        a2 += x0[2 * IN_CH + k] * w;
        a3 += x0[3 * IN_CH + k] * w;
    }
    size_t o = (size_t)n0 * HID + j;
    s1[o]           = dis[n0]     * a0;
    s1[o + HID]     = dis[n0 + 1] * a1;
    s1[o + 2 * HID] = dis[n0 + 2] * a2;
    s1[o + 3 * HID] = dis[n0 + 3] * a3;
}

// ---------------- gather layer 1 + ELU: h1[v][j] = ELU(dis[v]*(s1[v][j] + Σ s1[u][j]) + b1[j])
// one wave per node (64 lanes = 64 features); 4 nodes/block; 25000 blocks exact.
__global__ __launch_bounds__(256) void gather1(const float* __restrict__ s1,
                                               const int* __restrict__ ptr,
                                               const int* __restrict__ srcs,
                                               const float* __restrict__ dis,
                                               const float* __restrict__ b1,
                                               float* __restrict__ h1) {
    const int j = threadIdx.x & 63;
    const int v = blockIdx.x * 4 + (threadIdx.x >> 6);
    float acc = s1[(size_t)v * HID + j];              // self-loop term
    int beg = (v > 0) ? ptr[v - 1] : 0;               // ptr is inclusive after fill
    int end = ptr[v];
    int k = beg;
    for (; k + 4 <= end; k += 4) {
        int u0 = srcs[k], u1 = srcs[k + 1], u2 = srcs[k + 2], u3 = srcs[k + 3];
        float f0 = s1[(size_t)u0 * HID + j];
        float f1 = s1[(size_t)u1 * HID + j];
        float f2 = s1[(size_t)u2 * HID + j];
        float f3 = s1[(size_t)u3 * HID + j];
        acc += f0 + f1 + f2 + f3;
    }
    for (; k < end; ++k) acc += s1[(size_t)srcs[k] * HID + j];
    float t = dis[v] * acc + b1[j];
    h1[(size_t)v * HID + j] = t > 0.f ? t : (expf(t) - 1.f);
}

// ---------------- GEMM2: s2[n][j] = dis[n] * (h1[n,:] @ W2[:,j]) ----------------
// block = 256 = 8 groups of 32 lanes; 4 rows/group; 32 rows/block; 3125 blocks exact.
__global__ __launch_bounds__(256) void gemm2(const float* __restrict__ h,
                                             const float* __restrict__ W2,
                                             const float* __restrict__ dis,
                                             float* __restrict__ s2) {
    const int j  = threadIdx.x & 31;
    const int g  = threadIdx.x >> 5;
    const int n0 = blockIdx.x * 32 + g * 4;
    const float* h0 = h + (size_t)n0 * HID;
    float a0 = 0.f, a1 = 0.f, a2 = 0.f, a3 = 0.f;
#pragma unroll 4
    for (int k = 0; k < HID; ++k) {
        float w = W2[k * OUTC + j];
        a0 += h0[k] * w;
        a1 += h0[HID + k] * w;
        a2 += h0[2 * HID + k] * w;
        a3 += h0[3 * HID + k] * w;
    }
    size_t o = (size_t)n0 * OUTC + j;
    s2[o]            = dis[n0]     * a0;
    s2[o + OUTC]     = dis[n0 + 1] * a1;
    s2[o + 2 * OUTC] = dis[n0 + 2] * a2;
    s2[o + 3 * OUTC] = dis[n0 + 3] * a3;
}

// ---------------- gather layer 2 + ELU + final projection ----------------
// 32 lanes per node; 8 nodes/block; 12500 blocks exact.
__global__ __launch_bounds__(256) void gather2(const float* __restrict__ s2,
                                               const int* __restrict__ ptr,
                                               const int* __restrict__ srcs,
                                               const float* __restrict__ dis,
                                               const float* __restrict__ b2,
                                               const float* __restrict__ Wc,
                                               const float* __restrict__ bc,
                                               float* __restrict__ out) {
    const int j = threadIdx.x & 31;
    const int v = blockIdx.x * 8 + (threadIdx.x >> 5);
    float acc = s2[(size_t)v * OUTC + j];             // self-loop term
    int beg = (v > 0) ? ptr[v - 1] : 0;
    int end = ptr[v];
    int k = beg;
    for (; k + 4 <= end; k += 4) {
        int u0 = srcs[k], u1 = srcs[k + 1], u2 = srcs[k + 2], u3 = srcs[k + 3];
        float f0 = s2[(size_t)u0 * OUTC + j];
        float f1 = s2[(size_t)u1 * OUTC + j];
        float f2 = s2[(size_t)u2 * OUTC + j];
        float f3 = s2[(size_t)u3 * OUTC + j];
        acc += f0 + f1 + f2 + f3;
    }
    for (; k < end; ++k) acc += s2[(size_t)srcs[k] * OUTC + j];
    float t = dis[v] * acc + b2[j];
    float hh = t > 0.f ? t : (expf(t) - 1.f);
    float p = hh * Wc[j];
#pragma unroll
    for (int off = 16; off > 0; off >>= 1) p += __shfl_xor(p, off, 64);  // stays within 32-lane half
    if (j == 0) out[v] = p + bc[0];
}

extern "C" void kernel_launch(void* const* d_in, const int* in_sizes, int n_in,
                              void* d_out, int out_size, void* d_ws, size_t ws_size,
                              hipStream_t stream) {
    const float* x  = (const float*)d_in[0];
    const int*   ei = (const int*)d_in[1];   // int32 (x64-disabled JAX)
    const float* W1 = (const float*)d_in[2];
    const float* b1 = (const float*)d_in[3];
    const float* W2 = (const float*)d_in[4];
    const float* b2 = (const float*)d_in[5];
    const float* Wc = (const float*)d_in[6];
    const float* bc = (const float*)d_in[7];
    float* out = (float*)d_out;

    const int* row = ei;            // edge_index[0] = source
    const int* col = ei + N_EDGES;  // edge_index[1] = target

    char* ws = (char*)d_ws;
    int*   deg  = (int*)  (ws + OFF_DEG);
    int*   ptr  = (int*)  (ws + OFF_PTR);
    int*   bsum = (int*)  (ws + OFF_BSUM);
    float* dis  = (float*)(ws + OFF_DIS);
    int*   srcs = (int*)  (ws + OFF_SRC);
    float* s1   = (float*)(ws + OFF_S1);
    float* h1   = (float*)(ws + OFF_H1);
    float* s2   = (float*)(ws + OFF_S1);   // reuse s1's slot (dead after gather1)

    hipMemsetAsync(deg, 0, (size_t)N_NODES * sizeof(int), stream);

    count_deg      <<<(N_EDGES + 255) / 256, 256, 0, stream>>>(col, deg);
    compute_dis    <<<NB, 256, 0, stream>>>(deg, dis);
    scan_block_sums<<<NB, 256, 0, stream>>>(deg, bsum);
    scan_bsum      <<<1, 512, 0, stream>>>(bsum);
    scan_block_scan<<<NB, 256, 0, stream>>>(deg, bsum, ptr);
    csr_fill       <<<(N_EDGES + 255) / 256, 256, 0, stream>>>(row, col, ptr, srcs);

    gemm1  <<<N_NODES / 16, 256, 0, stream>>>(x, W1, dis, s1);
    gather1<<<N_NODES / 4, 256, 0, stream>>>(s1, ptr, srcs, dis, b1, h1);
    gemm2  <<<N_NODES / 32, 256, 0, stream>>>(h1, W2, dis, s2);
    gather2<<<N_NODES / 8, 256, 0, stream>>>(s2, ptr, srcs, dis, b2, Wc, bc, out);
}

// Round 3
// 898.985 us; speedup vs baseline: 1.7877x; 1.1244x over previous
//
#include <hip/hip_runtime.h>
#include <math.h>

#define N_NODES 100000
#define N_EDGES 3200000
#define IN_CH   256
#define HID     64
#define OUTC    32
#define NB      ((N_NODES + 255) / 256)   // 391 scan blocks

// ---------------- workspace layout (bytes) ----------------
static constexpr size_t align256(size_t x) { return (x + 255) & ~(size_t)255; }
static constexpr size_t OFF_DEG  = 0;                                          // N ints
static constexpr size_t OFF_PTR  = OFF_DEG  + align256((size_t)N_NODES * 4);   // N ints
static constexpr size_t OFF_BSUM = OFF_PTR  + align256((size_t)N_NODES * 4);   // 512 ints
static constexpr size_t OFF_DIS  = OFF_BSUM + align256(512 * 4);               // N floats
static constexpr size_t OFF_SRC  = OFF_DIS  + align256((size_t)N_NODES * 4);   // E ints
static constexpr size_t OFF_S1   = OFF_SRC  + align256((size_t)N_EDGES * 4);   // N*64 floats (reused as s2)
static constexpr size_t OFF_H1   = OFF_S1   + (size_t)N_NODES * HID * 4;       // N*64 floats

// ---------------- degree ----------------
__global__ __launch_bounds__(256) void count_deg(const int* __restrict__ col,
                                                 int* __restrict__ deg) {
    unsigned e = blockIdx.x * 256u + threadIdx.x;
    if (e < N_EDGES) atomicAdd(&deg[col[e]], 1);
}

__global__ __launch_bounds__(256) void compute_dis(const int* __restrict__ deg,
                                                   float* __restrict__ dis) {
    unsigned v = blockIdx.x * 256u + threadIdx.x;
    if (v < N_NODES) dis[v] = rsqrtf((float)deg[v] + 1.0f);  // +1 self-loop
}

// ---------------- 3-kernel exclusive scan of deg -> ptr ----------------
__global__ __launch_bounds__(256) void scan_block_sums(const int* __restrict__ deg,
                                                       int* __restrict__ bsum) {
    __shared__ int buf[256];
    unsigned i = blockIdx.x * 256u + threadIdx.x;
    int v = (i < N_NODES) ? deg[i] : 0;
    buf[threadIdx.x] = v;
    __syncthreads();
    for (int off = 128; off > 0; off >>= 1) {
        if (threadIdx.x < (unsigned)off) buf[threadIdx.x] += buf[threadIdx.x + off];
        __syncthreads();
    }
    if (threadIdx.x == 0) bsum[blockIdx.x] = buf[0];
}

__global__ __launch_bounds__(512) void scan_bsum(int* __restrict__ bsum) {
    __shared__ int buf[512];
    int t = threadIdx.x;
    int v = (t < NB) ? bsum[t] : 0;
    buf[t] = v;
    __syncthreads();
    for (int off = 1; off < 512; off <<= 1) {
        int add = (t >= off) ? buf[t - off] : 0;
        __syncthreads();
        buf[t] += add;
        __syncthreads();
    }
    if (t < NB) bsum[t] = buf[t] - v;  // exclusive
}

__global__ __launch_bounds__(256) void scan_block_scan(const int* __restrict__ deg,
                                                       const int* __restrict__ bsum,
                                                       int* __restrict__ ptr) {
    __shared__ int buf[256];
    unsigned i = blockIdx.x * 256u + threadIdx.x;
    int v = (i < N_NODES) ? deg[i] : 0;
    buf[threadIdx.x] = v;
    __syncthreads();
    for (int off = 1; off < 256; off <<= 1) {
        int add = (threadIdx.x >= (unsigned)off) ? buf[threadIdx.x - off] : 0;
        __syncthreads();
        buf[threadIdx.x] += add;
        __syncthreads();
    }
    if (i < N_NODES) ptr[i] = bsum[blockIdx.x] + buf[threadIdx.x] - v;  // exclusive
}

// ---------------- CSR fill: ptr doubles as cursor (post: ptr[v] = segment end) ----
__global__ __launch_bounds__(256) void csr_fill(const int* __restrict__ row,
                                                const int* __restrict__ col,
                                                int* __restrict__ ptr,
                                                int* __restrict__ srcs) {
    unsigned e = blockIdx.x * 256u + threadIdx.x;
    if (e < N_EDGES) {
        int v = col[e];
        int pos = atomicAdd(&ptr[v], 1);
        srcs[pos] = row[e];
    }
}

// ---------------- GEMM1: s1[n][j] = dis[n] * (x[n,:] @ W1[:,j]) ----------------
// W1 (64 KB) staged in LDS once; x rows read via SCALAR loads (wave-uniform rows);
// inner loop = pure v_fmac with one SGPR operand + ds_read on the LDS pipe.
// block = 256 = 4 waves; 8 rows/wave; 32 rows/block; 3125 blocks exact.
__global__ __launch_bounds__(256) void gemm1(const float* __restrict__ x,
                                             const float* __restrict__ W1,
                                             const float* __restrict__ dis,
                                             float* __restrict__ s1) {
    __shared__ float wlds[IN_CH * HID];  // 64 KB, [k][j]

    const int t = threadIdx.x;
    // stage W1 -> LDS, coalesced float4
    {
        const float4* w4 = (const float4*)W1;
        float4* l4 = (float4*)wlds;
#pragma unroll
        for (int i = 0; i < 16; ++i) l4[i * 256 + t] = w4[i * 256 + t];
    }
    __syncthreads();

    const int j = t & 63;
    const int g = __builtin_amdgcn_readfirstlane(t >> 6);  // wave id: force SGPR
    const int rbase = blockIdx.x * 32 + g * 8;
    const float4* xr4 = (const float4*)(x + (size_t)rbase * IN_CH);  // row r at r*64 float4s

    float acc[8] = {0.f, 0.f, 0.f, 0.f, 0.f, 0.f, 0.f, 0.f};

#pragma unroll 2
    for (int k4 = 0; k4 < IN_CH / 4; ++k4) {
        float4 xv[8];
#pragma unroll
        for (int r = 0; r < 8; ++r) xv[r] = xr4[r * (IN_CH / 4) + k4];  // uniform -> s_load_dwordx4
        const int kb = k4 * 4;
        {
            float w = wlds[(kb + 0) * HID + j];
#pragma unroll
            for (int r = 0; r < 8; ++r) acc[r] += xv[r].x * w;
        }
        {
            float w = wlds[(kb + 1) * HID + j];
#pragma unroll
            for (int r = 0; r < 8; ++r) acc[r] += xv[r].y * w;
        }
        {
            float w = wlds[(kb + 2) * HID + j];
#pragma unroll
            for (int r = 0; r < 8; ++r) acc[r] += xv[r].z * w;
        }
        {
            float w = wlds[(kb + 3) * HID + j];
#pragma unroll
            for (int r = 0; r < 8; ++r) acc[r] += xv[r].w * w;
        }
    }

#pragma unroll
    for (int r = 0; r < 8; ++r) {
        s1[(size_t)(rbase + r) * HID + j] = dis[rbase + r] * acc[r];
    }
}

// ---------------- gather layer 1 + ELU ----------------
// one wave per node (64 lanes = 64 features); v wave-uniform -> ptr/srcs scalar loads;
// 8-deep unrolled row loads for latency hiding. 4 nodes/block; 25000 blocks exact.
__global__ __launch_bounds__(256) void gather1(const float* __restrict__ s1,
                                               const int* __restrict__ ptr,
                                               const int* __restrict__ srcs,
                                               const float* __restrict__ dis,
                                               const float* __restrict__ b1,
                                               float* __restrict__ h1) {
    const int j = threadIdx.x & 63;
    const int v = __builtin_amdgcn_readfirstlane(blockIdx.x * 4 + (threadIdx.x >> 6));
    float acc = s1[(size_t)v * HID + j];              // self-loop term
    const int beg = (v > 0) ? ptr[v - 1] : 0;         // ptr inclusive post-fill
    const int end = ptr[v];
    int k = beg;
    for (; k + 8 <= end; k += 8) {
        int u0 = srcs[k],     u1 = srcs[k + 1], u2 = srcs[k + 2], u3 = srcs[k + 3];
        int u4 = srcs[k + 4], u5 = srcs[k + 5], u6 = srcs[k + 6], u7 = srcs[k + 7];
        float f0 = s1[(size_t)u0 * HID + j];
        float f1 = s1[(size_t)u1 * HID + j];
        float f2 = s1[(size_t)u2 * HID + j];
        float f3 = s1[(size_t)u3 * HID + j];
        float f4 = s1[(size_t)u4 * HID + j];
        float f5 = s1[(size_t)u5 * HID + j];
        float f6 = s1[(size_t)u6 * HID + j];
        float f7 = s1[(size_t)u7 * HID + j];
        acc += ((f0 + f1) + (f2 + f3)) + ((f4 + f5) + (f6 + f7));
    }
    for (; k < end; ++k) acc += s1[(size_t)srcs[k] * HID + j];
    float tt = dis[v] * acc + b1[j];
    h1[(size_t)v * HID + j] = tt > 0.f ? tt : (expf(tt) - 1.f);
}

// ---------------- GEMM2: s2[n][j] = dis[n] * (h1[n,:] @ W2[:,j]) ----------------
__global__ __launch_bounds__(256) void gemm2(const float* __restrict__ h,
                                             const float* __restrict__ W2,
                                             const float* __restrict__ dis,
                                             float* __restrict__ s2) {
    const int j  = threadIdx.x & 31;
    const int g  = threadIdx.x >> 5;
    const int n0 = blockIdx.x * 32 + g * 4;
    const float* h0 = h + (size_t)n0 * HID;
    float a0 = 0.f, a1 = 0.f, a2 = 0.f, a3 = 0.f;
#pragma unroll 4
    for (int k = 0; k < HID; ++k) {
        float w = W2[k * OUTC + j];
        a0 += h0[k] * w;
        a1 += h0[HID + k] * w;
        a2 += h0[2 * HID + k] * w;
        a3 += h0[3 * HID + k] * w;
    }
    size_t o = (size_t)n0 * OUTC + j;
    s2[o]            = dis[n0]     * a0;
    s2[o + OUTC]     = dis[n0 + 1] * a1;
    s2[o + 2 * OUTC] = dis[n0 + 2] * a2;
    s2[o + 3 * OUTC] = dis[n0 + 3] * a3;
}

// ---------------- gather layer 2 + ELU + final projection ----------------
// 32 lanes per node; 8 nodes/block; 12500 blocks exact.
__global__ __launch_bounds__(256) void gather2(const float* __restrict__ s2,
                                               const int* __restrict__ ptr,
                                               const int* __restrict__ srcs,
                                               const float* __restrict__ dis,
                                               const float* __restrict__ b2,
                                               const float* __restrict__ Wc,
                                               const float* __restrict__ bc,
                                               float* __restrict__ out) {
    const int j = threadIdx.x & 31;
    const int v = blockIdx.x * 8 + (threadIdx.x >> 5);
    float acc = s2[(size_t)v * OUTC + j];             // self-loop term
    const int beg = (v > 0) ? ptr[v - 1] : 0;
    const int end = ptr[v];
    int k = beg;
    for (; k + 8 <= end; k += 8) {
        int u0 = srcs[k],     u1 = srcs[k + 1], u2 = srcs[k + 2], u3 = srcs[k + 3];
        int u4 = srcs[k + 4], u5 = srcs[k + 5], u6 = srcs[k + 6], u7 = srcs[k + 7];
        float f0 = s2[(size_t)u0 * OUTC + j];
        float f1 = s2[(size_t)u1 * OUTC + j];
        float f2 = s2[(size_t)u2 * OUTC + j];
        float f3 = s2[(size_t)u3 * OUTC + j];
        float f4 = s2[(size_t)u4 * OUTC + j];
        float f5 = s2[(size_t)u5 * OUTC + j];
        float f6 = s2[(size_t)u6 * OUTC + j];
        float f7 = s2[(size_t)u7 * OUTC + j];
        acc += ((f0 + f1) + (f2 + f3)) + ((f4 + f5) + (f6 + f7));
    }
    for (; k < end; ++k) acc += s2[(size_t)srcs[k] * OUTC + j];
    float t = dis[v] * acc + b2[j];
    float hh = t > 0.f ? t : (expf(t) - 1.f);
    float p = hh * Wc[j];
#pragma unroll
    for (int off = 16; off > 0; off >>= 1) p += __shfl_xor(p, off, 64);  // stays in 32-lane half
    if (j == 0) out[v] = p + bc[0];
}

extern "C" void kernel_launch(void* const* d_in, const int* in_sizes, int n_in,
                              void* d_out, int out_size, void* d_ws, size_t ws_size,
                              hipStream_t stream) {
    const float* x  = (const float*)d_in[0];
    const int*   ei = (const int*)d_in[1];
    const float* W1 = (const float*)d_in[2];
    const float* b1 = (const float*)d_in[3];
    const float* W2 = (const float*)d_in[4];
    const float* b2 = (const float*)d_in[5];
    const float* Wc = (const float*)d_in[6];
    const float* bc = (const float*)d_in[7];
    float* out = (float*)d_out;

    const int* row = ei;            // edge_index[0] = source
    const int* col = ei + N_EDGES;  // edge_index[1] = target

    char* ws = (char*)d_ws;
    int*   deg  = (int*)  (ws + OFF_DEG);
    int*   ptr  = (int*)  (ws + OFF_PTR);
    int*   bsum = (int*)  (ws + OFF_BSUM);
    float* dis  = (float*)(ws + OFF_DIS);
    int*   srcs = (int*)  (ws + OFF_SRC);
    float* s1   = (float*)(ws + OFF_S1);
    float* h1   = (float*)(ws + OFF_H1);
    float* s2   = (float*)(ws + OFF_S1);   // reuse (dead after gather1)

    hipMemsetAsync(deg, 0, (size_t)N_NODES * sizeof(int), stream);

    count_deg      <<<(N_EDGES + 255) / 256, 256, 0, stream>>>(col, deg);
    compute_dis    <<<NB, 256, 0, stream>>>(deg, dis);
    scan_block_sums<<<NB, 256, 0, stream>>>(deg, bsum);
    scan_bsum      <<<1, 512, 0, stream>>>(bsum);
    scan_block_scan<<<NB, 256, 0, stream>>>(deg, bsum, ptr);
    csr_fill       <<<(N_EDGES + 255) / 256, 256, 0, stream>>>(row, col, ptr, srcs);

    gemm1  <<<N_NODES / 32, 256, 0, stream>>>(x, W1, dis, s1);
    gather1<<<N_NODES / 4, 256, 0, stream>>>(s1, ptr, srcs, dis, b1, h1);
    gemm2  <<<N_NODES / 32, 256, 0, stream>>>(h1, W2, dis, s2);
    gather2<<<N_NODES / 8, 256, 0, stream>>>(s2, ptr, srcs, dis, b2, Wc, bc, out);
}

// Round 4
// 630.517 us; speedup vs baseline: 2.5488x; 1.4258x over previous
//
#include <hip/hip_runtime.h>
#include <math.h>

#define N_NODES 100000
#define N_EDGES 3200000
#define IN_CH   256
#define HID     64
#define OUTC    32
#define NB      ((N_NODES + 255) / 256)   // 391 (scan blocks, also node buckets)
#define NBUCK   ((N_NODES + 255) / 256)   // 391 buckets of 256 nodes (bucket = dst >> 8)
#define CHUNK   8192                      // edges per partition block
#define CAP     9216                      // bucket capacity: mean 8192, sigma ~90 -> +11 sigma

// ---------------- workspace layout (bytes) ----------------
static constexpr size_t align256(size_t x) { return (x + 255) & ~(size_t)255; }
static constexpr size_t OFF_DEG  = 0;                                          // N ints
static constexpr size_t OFF_PTR  = OFF_DEG  + align256((size_t)N_NODES * 4);   // N ints (exclusive)
static constexpr size_t OFF_BSUM = OFF_PTR  + align256((size_t)N_NODES * 4);   // 512 ints
static constexpr size_t OFF_GCUR = OFF_BSUM + align256(512 * 4);               // NBUCK ints
static constexpr size_t OFF_DIS  = OFF_GCUR + align256((size_t)NBUCK * 4);     // N floats
static constexpr size_t OFF_SRC  = OFF_DIS  + align256((size_t)N_NODES * 4);   // E ints
static constexpr size_t OFF_S1   = OFF_SRC  + align256((size_t)N_EDGES * 4);   // N*64 floats (s1 / s2)
static constexpr size_t OFF_H1   = OFF_S1   + (size_t)N_NODES * HID * 4;       // N*64 floats
// partition buffer (NBUCK*CAP ints = 14.4 MB) aliases the s1/h1 region (dead until gemm1)

// ---------------- bucket cursor init: gcur[b] = b*CAP ----------------
__global__ __launch_bounds__(256) void bucket_init(int* __restrict__ gcur) {
    int b = blockIdx.x * 256 + threadIdx.x;
    if (b < NBUCK) gcur[b] = b * CAP;
}

// ---------------- phase A: partition edges into coarse dst-buckets ----------------
// packed entry: src (17 bits) | dst_low8 << 17
__global__ __launch_bounds__(256) void partition_edges(const int* __restrict__ row,
                                                       const int* __restrict__ col,
                                                       int* __restrict__ gcur,
                                                       int* __restrict__ part) {
    __shared__ int lhist[NBUCK];
    __shared__ int lbase[NBUCK];
    __shared__ int lrank[NBUCK];
    const int t  = threadIdx.x;
    const int e0 = blockIdx.x * CHUNK;
    const int e1 = min(e0 + CHUNK, N_EDGES);
    for (int i = t; i < NBUCK; i += 256) { lhist[i] = 0; lrank[i] = 0; }
    __syncthreads();
    // pass 1: per-bucket histogram
    for (int e = e0 + t; e < e1; e += 256) {
        atomicAdd(&lhist[col[e] >> 8], 1);
    }
    __syncthreads();
    // reserve contiguous global runs per bucket
    for (int i = t; i < NBUCK; i += 256) {
        int c = lhist[i];
        lbase[i] = (c > 0) ? atomicAdd(&gcur[i], c) : 0;
    }
    __syncthreads();
    // pass 2: scatter packed entries into reserved runs
    for (int e = e0 + t; e < e1; e += 256) {
        int d = col[e];
        int b = d >> 8;
        int r = atomicAdd(&lrank[b], 1);
        part[lbase[b] + r] = row[e] | ((d & 255) << 17);
    }
}

// ---------------- phase B1: per-node degree from bucket data (dense writes) ----------
__global__ __launch_bounds__(256) void bucket_hist(const int* __restrict__ gcur,
                                                   const int* __restrict__ part,
                                                   int* __restrict__ deg) {
    __shared__ int lh[256];
    const int b = blockIdx.x;
    lh[threadIdx.x] = 0;
    __syncthreads();
    const int cnt = gcur[b] - b * CAP;
    for (int i = threadIdx.x; i < cnt; i += 256)
        atomicAdd(&lh[part[(size_t)b * CAP + i] >> 17], 1);
    __syncthreads();
    int v = b * 256 + threadIdx.x;
    if (v < N_NODES) deg[v] = lh[threadIdx.x];
}

__global__ __launch_bounds__(256) void compute_dis(const int* __restrict__ deg,
                                                   float* __restrict__ dis) {
    unsigned v = blockIdx.x * 256u + threadIdx.x;
    if (v < N_NODES) dis[v] = rsqrtf((float)deg[v] + 1.0f);  // +1 self-loop
}

// ---------------- 3-kernel exclusive scan of deg -> ptr ----------------
__global__ __launch_bounds__(256) void scan_block_sums(const int* __restrict__ deg,
                                                       int* __restrict__ bsum) {
    __shared__ int buf[256];
    unsigned i = blockIdx.x * 256u + threadIdx.x;
    int v = (i < N_NODES) ? deg[i] : 0;
    buf[threadIdx.x] = v;
    __syncthreads();
    for (int off = 128; off > 0; off >>= 1) {
        if (threadIdx.x < (unsigned)off) buf[threadIdx.x] += buf[threadIdx.x + off];
        __syncthreads();
    }
    if (threadIdx.x == 0) bsum[blockIdx.x] = buf[0];
}

__global__ __launch_bounds__(512) void scan_bsum(int* __restrict__ bsum) {
    __shared__ int buf[512];
    int t = threadIdx.x;
    int v = (t < NB) ? bsum[t] : 0;
    buf[t] = v;
    __syncthreads();
    for (int off = 1; off < 512; off <<= 1) {
        int add = (t >= off) ? buf[t - off] : 0;
        __syncthreads();
        buf[t] += add;
        __syncthreads();
    }
    if (t < NB) bsum[t] = buf[t] - v;  // exclusive
}

__global__ __launch_bounds__(256) void scan_block_scan(const int* __restrict__ deg,
                                                       const int* __restrict__ bsum,
                                                       int* __restrict__ ptr) {
    __shared__ int buf[256];
    unsigned i = blockIdx.x * 256u + threadIdx.x;
    int v = (i < N_NODES) ? deg[i] : 0;
    buf[threadIdx.x] = v;
    __syncthreads();
    for (int off = 1; off < 256; off <<= 1) {
        int add = (threadIdx.x >= (unsigned)off) ? buf[threadIdx.x - off] : 0;
        __syncthreads();
        buf[threadIdx.x] += add;
        __syncthreads();
    }
    if (i < N_NODES) ptr[i] = bsum[blockIdx.x] + buf[threadIdx.x] - v;  // exclusive
}

// ---------------- phase B2: fill srcs; writes confined to ~32KB window/block -------
__global__ __launch_bounds__(256) void bucket_fill(const int* __restrict__ gcur,
                                                   const int* __restrict__ part,
                                                   const int* __restrict__ ptr,
                                                   int* __restrict__ srcs) {
    __shared__ int lcur[256];
    const int b = blockIdx.x;
    lcur[threadIdx.x] = 0;
    __syncthreads();
    const int cnt = gcur[b] - b * CAP;
    for (int i = threadIdx.x; i < cnt; i += 256) {
        int p    = part[(size_t)b * CAP + i];
        int dlow = p >> 17;
        int src  = p & 0x1FFFF;
        int r    = atomicAdd(&lcur[dlow], 1);        // LDS cursor
        srcs[ptr[b * 256 + dlow] + r] = src;
    }
}

// ---------------- GEMM1: s1[n][j] = dis[n] * (x[n,:] @ W1[:,j]) ----------------
__global__ __launch_bounds__(256) void gemm1(const float* __restrict__ x,
                                             const float* __restrict__ W1,
                                             const float* __restrict__ dis,
                                             float* __restrict__ s1) {
    __shared__ float wlds[IN_CH * HID];  // 64 KB, [k][j]
    const int t = threadIdx.x;
    {
        const float4* w4 = (const float4*)W1;
        float4* l4 = (float4*)wlds;
#pragma unroll
        for (int i = 0; i < 16; ++i) l4[i * 256 + t] = w4[i * 256 + t];
    }
    __syncthreads();

    const int j = t & 63;
    const int g = __builtin_amdgcn_readfirstlane(t >> 6);
    const int rbase = blockIdx.x * 32 + g * 8;
    const float4* xr4 = (const float4*)(x + (size_t)rbase * IN_CH);

    float acc[8] = {0.f, 0.f, 0.f, 0.f, 0.f, 0.f, 0.f, 0.f};
#pragma unroll 2
    for (int k4 = 0; k4 < IN_CH / 4; ++k4) {
        float4 xv[8];
#pragma unroll
        for (int r = 0; r < 8; ++r) xv[r] = xr4[r * (IN_CH / 4) + k4];
        const int kb = k4 * 4;
        {
            float w = wlds[(kb + 0) * HID + j];
#pragma unroll
            for (int r = 0; r < 8; ++r) acc[r] += xv[r].x * w;
        }
        {
            float w = wlds[(kb + 1) * HID + j];
#pragma unroll
            for (int r = 0; r < 8; ++r) acc[r] += xv[r].y * w;
        }
        {
            float w = wlds[(kb + 2) * HID + j];
#pragma unroll
            for (int r = 0; r < 8; ++r) acc[r] += xv[r].z * w;
        }
        {
            float w = wlds[(kb + 3) * HID + j];
#pragma unroll
            for (int r = 0; r < 8; ++r) acc[r] += xv[r].w * w;
        }
    }
#pragma unroll
    for (int r = 0; r < 8; ++r) {
        s1[(size_t)(rbase + r) * HID + j] = dis[rbase + r] * acc[r];
    }
}

// ---------------- gather layer 1 + ELU ----------------
__global__ __launch_bounds__(256) void gather1(const float* __restrict__ s1,
                                               const int* __restrict__ ptr,
                                               const int* __restrict__ srcs,
                                               const float* __restrict__ dis,
                                               const float* __restrict__ b1,
                                               float* __restrict__ h1) {
    const int j = threadIdx.x & 63;
    const int v = __builtin_amdgcn_readfirstlane(blockIdx.x * 4 + (threadIdx.x >> 6));
    float acc = s1[(size_t)v * HID + j];              // self-loop term
    const int beg = ptr[v];
    const int end = (v + 1 < N_NODES) ? ptr[v + 1] : N_EDGES;
    int k = beg;
    for (; k + 8 <= end; k += 8) {
        int u0 = srcs[k],     u1 = srcs[k + 1], u2 = srcs[k + 2], u3 = srcs[k + 3];
        int u4 = srcs[k + 4], u5 = srcs[k + 5], u6 = srcs[k + 6], u7 = srcs[k + 7];
        float f0 = s1[(size_t)u0 * HID + j];
        float f1 = s1[(size_t)u1 * HID + j];
        float f2 = s1[(size_t)u2 * HID + j];
        float f3 = s1[(size_t)u3 * HID + j];
        float f4 = s1[(size_t)u4 * HID + j];
        float f5 = s1[(size_t)u5 * HID + j];
        float f6 = s1[(size_t)u6 * HID + j];
        float f7 = s1[(size_t)u7 * HID + j];
        acc += ((f0 + f1) + (f2 + f3)) + ((f4 + f5) + (f6 + f7));
    }
    for (; k < end; ++k) acc += s1[(size_t)srcs[k] * HID + j];
    float tt = dis[v] * acc + b1[j];
    h1[(size_t)v * HID + j] = tt > 0.f ? tt : (expf(tt) - 1.f);
}

// ---------------- GEMM2: s2[n][j] = dis[n] * (h1[n,:] @ W2[:,j]) ----------------
__global__ __launch_bounds__(256) void gemm2(const float* __restrict__ h,
                                             const float* __restrict__ W2,
                                             const float* __restrict__ dis,
                                             float* __restrict__ s2) {
    const int j  = threadIdx.x & 31;
    const int g  = threadIdx.x >> 5;
    const int n0 = blockIdx.x * 32 + g * 4;
    const float* h0 = h + (size_t)n0 * HID;
    float a0 = 0.f, a1 = 0.f, a2 = 0.f, a3 = 0.f;
#pragma unroll 4
    for (int k = 0; k < HID; ++k) {
        float w = W2[k * OUTC + j];
        a0 += h0[k] * w;
        a1 += h0[HID + k] * w;
        a2 += h0[2 * HID + k] * w;
        a3 += h0[3 * HID + k] * w;
    }
    size_t o = (size_t)n0 * OUTC + j;
    s2[o]            = dis[n0]     * a0;
    s2[o + OUTC]     = dis[n0 + 1] * a1;
    s2[o + 2 * OUTC] = dis[n0 + 2] * a2;
    s2[o + 3 * OUTC] = dis[n0 + 3] * a3;
}

// ---------------- gather layer 2 + ELU + final projection ----------------
__global__ __launch_bounds__(256) void gather2(const float* __restrict__ s2,
                                               const int* __restrict__ ptr,
                                               const int* __restrict__ srcs,
                                               const float* __restrict__ dis,
                                               const float* __restrict__ b2,
                                               const float* __restrict__ Wc,
                                               const float* __restrict__ bc,
                                               float* __restrict__ out) {
    const int j = threadIdx.x & 31;
    const int v = blockIdx.x * 8 + (threadIdx.x >> 5);
    float acc = s2[(size_t)v * OUTC + j];             // self-loop term
    const int beg = ptr[v];
    const int end = (v + 1 < N_NODES) ? ptr[v + 1] : N_EDGES;
    int k = beg;
    for (; k + 8 <= end; k += 8) {
        int u0 = srcs[k],     u1 = srcs[k + 1], u2 = srcs[k + 2], u3 = srcs[k + 3];
        int u4 = srcs[k + 4], u5 = srcs[k + 5], u6 = srcs[k + 6], u7 = srcs[k + 7];
        float f0 = s2[(size_t)u0 * OUTC + j];
        float f1 = s2[(size_t)u1 * OUTC + j];
        float f2 = s2[(size_t)u2 * OUTC + j];
        float f3 = s2[(size_t)u3 * OUTC + j];
        float f4 = s2[(size_t)u4 * OUTC + j];
        float f5 = s2[(size_t)u5 * OUTC + j];
        float f6 = s2[(size_t)u6 * OUTC + j];
        float f7 = s2[(size_t)u7 * OUTC + j];
        acc += ((f0 + f1) + (f2 + f3)) + ((f4 + f5) + (f6 + f7));
    }
    for (; k < end; ++k) acc += s2[(size_t)srcs[k] * OUTC + j];
    float t = dis[v] * acc + b2[j];
    float hh = t > 0.f ? t : (expf(t) - 1.f);
    float p = hh * Wc[j];
#pragma unroll
    for (int off = 16; off > 0; off >>= 1) p += __shfl_xor(p, off, 64);
    if (j == 0) out[v] = p + bc[0];
}

extern "C" void kernel_launch(void* const* d_in, const int* in_sizes, int n_in,
                              void* d_out, int out_size, void* d_ws, size_t ws_size,
                              hipStream_t stream) {
    const float* x  = (const float*)d_in[0];
    const int*   ei = (const int*)d_in[1];
    const float* W1 = (const float*)d_in[2];
    const float* b1 = (const float*)d_in[3];
    const float* W2 = (const float*)d_in[4];
    const float* b2 = (const float*)d_in[5];
    const float* Wc = (const float*)d_in[6];
    const float* bc = (const float*)d_in[7];
    float* out = (float*)d_out;

    const int* row = ei;            // edge_index[0] = source
    const int* col = ei + N_EDGES;  // edge_index[1] = target

    char* ws = (char*)d_ws;
    int*   deg  = (int*)  (ws + OFF_DEG);
    int*   ptr  = (int*)  (ws + OFF_PTR);
    int*   bsum = (int*)  (ws + OFF_BSUM);
    int*   gcur = (int*)  (ws + OFF_GCUR);
    float* dis  = (float*)(ws + OFF_DIS);
    int*   srcs = (int*)  (ws + OFF_SRC);
    float* s1   = (float*)(ws + OFF_S1);
    float* h1   = (float*)(ws + OFF_H1);
    float* s2   = (float*)(ws + OFF_S1);   // reuse (dead after gather1)
    int*   part = (int*)  (ws + OFF_S1);   // partition buffer aliases s1/h1 (dead before gemm1)

    bucket_init    <<<(NBUCK + 255) / 256, 256, 0, stream>>>(gcur);
    partition_edges<<<(N_EDGES + CHUNK - 1) / CHUNK, 256, 0, stream>>>(row, col, gcur, part);
    bucket_hist    <<<NBUCK, 256, 0, stream>>>(gcur, part, deg);
    compute_dis    <<<NB, 256, 0, stream>>>(deg, dis);
    scan_block_sums<<<NB, 256, 0, stream>>>(deg, bsum);
    scan_bsum      <<<1, 512, 0, stream>>>(bsum);
    scan_block_scan<<<NB, 256, 0, stream>>>(deg, bsum, ptr);
    bucket_fill    <<<NBUCK, 256, 0, stream>>>(gcur, part, ptr, srcs);

    gemm1  <<<N_NODES / 32, 256, 0, stream>>>(x, W1, dis, s1);
    gather1<<<N_NODES / 4, 256, 0, stream>>>(s1, ptr, srcs, dis, b1, h1);
    gemm2  <<<N_NODES / 32, 256, 0, stream>>>(h1, W2, dis, s2);
    gather2<<<N_NODES / 8, 256, 0, stream>>>(s2, ptr, srcs, dis, b2, Wc, bc, out);
}